// Round 18
// baseline (119.130 us; speedup 1.0000x reference)
//
#include <hip/hip_runtime.h>
#include <math.h>

// ManifoldHyperConnectionFuse on MI355X — R17: uncapped occupancy + 17KB LDS.
// R16 post-mortem: FETCH halved (tile reuse works) but occupancy stuck at
// 40%: achieved occupancy has tracked launch_bounds' 2nd arg (x0.8) in every
// round -> the arg CAPS waves/EU (and triggers spill-throttle when pushed).
// R17: (a) drop the 2nd arg entirely (R0/R1 precedent: allocator emits
// ~need, no throttle), (b) NTOK=4 -> fp32 tile 16KB, LDS ~17KB -> resource
// cap rises to 8 blocks/CU = 32 waves = 100%. Grid 8192. Per-token VALU
// unchanged; the play is purely 2x resident waves to hide LDS/L2 latency.
// Everything else R16: bulk stage, wave-owns-token, DPP reduce, d_ws bf16
// weight table, phase C from LDS tile.

#define NTOK 4

__device__ __forceinline__ unsigned short f2bf(float f) {
    unsigned int u = __float_as_uint(f);
    return (unsigned short)((u + 0x7FFFu + ((u >> 16) & 1u)) >> 16);
}
__device__ __forceinline__ float bflo(unsigned int u) {
    return __uint_as_float(u << 16);
}
__device__ __forceinline__ float bfhi(unsigned int u) {
    return __uint_as_float(u & 0xffff0000u);
}
__device__ __forceinline__ float sigmoid_f(float z) {
    return 1.0f / (1.0f + __expf(-z));
}

// sum over each aligned 16-lane row via DPP row_ror (VALU-only)
__device__ __forceinline__ float row16_sum(float x) {
    x += __int_as_float(__builtin_amdgcn_update_dpp(
        0, __float_as_int(x), 0x121, 0xf, 0xf, false)); // row_ror:1
    x += __int_as_float(__builtin_amdgcn_update_dpp(
        0, __float_as_int(x), 0x122, 0xf, 0xf, false)); // row_ror:2
    x += __int_as_float(__builtin_amdgcn_update_dpp(
        0, __float_as_int(x), 0x124, 0xf, 0xf, false)); // row_ror:4
    x += __int_as_float(__builtin_amdgcn_update_dpp(
        0, __float_as_int(x), 0x128, 0xf, 0xf, false)); // row_ror:8
    return x;
}

// ---- prep: fold alpha*nw*w -> bf16 wt[24][1024] (n-major) in d_ws ----
__global__ __launch_bounds__(256)
void prep_kernel(const float* __restrict__ nw,
                 const float* __restrict__ w,
                 const float* __restrict__ alpha,
                 unsigned short* __restrict__ wt)
{
    const int tid = blockIdx.x * 256 + threadIdx.x;   // 6144 threads
    const int flat = 4 * tid;                          // w is [k][n], flat=k*24+n
    const float4 w4 = *(const float4*)(w + flat);
    const float a0 = alpha[0], a1 = alpha[1], a2 = alpha[2];
    const float vals[4] = {w4.x, w4.y, w4.z, w4.w};
    #pragma unroll
    for (int c = 0; c < 4; ++c) {
        const int f = flat + c;
        const int k = f / 24;
        const int n = f - 24 * k;
        const float as = (n < 4) ? a0 : ((n < 8) ? a1 : a2);
        wt[n * 1024 + k] = f2bf(as * nw[k] * vals[c]);
    }
}

__global__ __launch_bounds__(256)
void mhc_kernel(const float* __restrict__ h,
                const unsigned short* __restrict__ wt,
                const float* __restrict__ beta,
                float* __restrict__ out)
{
    const int tid  = threadIdx.x;
    const int lane = tid & 63;
    const int wv   = tid >> 6;     // wave id: owns token wv
    const int ksl  = lane & 15;    // k-slice lane
    const int ng   = lane >> 4;    // n-group (6 n's each)

    __shared__ float tile[NTOK * 1024];   // 16 KB h-tile
    __shared__ float Hpart[NTOK][28];     // [0:24) H, [24] r2
    __shared__ float smalls[NTOK][26];    // Hpre, Hpost, P

    const long tok0 = (long)blockIdx.x * NTOK;

    // ---- bulk stage: 4 x (256thr x 16B) = 16KB, all loads in flight ----
    {
        const float* src = h + tok0 * 1024 + 4 * tid;
        float4 st[NTOK];
        #pragma unroll
        for (int i = 0; i < NTOK; ++i)
            st[i] = *(const float4*)(src + 1024 * i);
        #pragma unroll
        for (int i = 0; i < NTOK; ++i)
            *(float4*)(tile + 1024 * i + 4 * tid) = st[i];
    }
    __syncthreads();

    // ---- phase A: x from LDS, w from d_ws (L2), wave owns 1 token ----
    const float* xt = tile + wv * 1024 + 4 * ksl;
    const unsigned short* pw = wt + (6 * ng) * 1024 + 4 * ksl;

    float acc[6];
    float r2 = 0.f;
    #pragma unroll
    for (int j = 0; j < 6; ++j) acc[j] = 0.f;

    uint2 wa[6];
    #pragma unroll
    for (int j = 0; j < 6; ++j) wa[j] = *(const uint2*)(pw + j * 1024);

    #pragma unroll 1
    for (int e = 0; e < 16; ++e) {
        const float4 xa = *(const float4*)(xt + 64 * e);   // LDS, broadcast
        uint2 wb[6];
        if (e + 1 < 16) {                 // next w chunk (L2-hot)
            const unsigned short* q = pw + (e + 1) * 64;
            #pragma unroll
            for (int j = 0; j < 6; ++j) wb[j] = *(const uint2*)(q + j * 1024);
        }

        #pragma unroll
        for (int j = 0; j < 6; ++j) {
            const float w0 = bflo(wa[j].x), w1 = bfhi(wa[j].x);
            const float w2 = bflo(wa[j].y), w3 = bfhi(wa[j].y);
            acc[j] = fmaf(xa.w, w3, fmaf(xa.z, w2,
                     fmaf(xa.y, w1, fmaf(xa.x, w0, acc[j]))));
        }
        r2 = fmaf(xa.w, xa.w, fmaf(xa.z, xa.z,
             fmaf(xa.y, xa.y, fmaf(xa.x, xa.x, r2))));

        #pragma unroll
        for (int j = 0; j < 6; ++j) wa[j] = wb[j];
    }

    // ---- DPP reduce over ksl -> FINAL H for this wave's token ----
    #pragma unroll
    for (int j = 0; j < 6; ++j) acc[j] = row16_sum(acc[j]);
    r2 = row16_sum(r2);

    if (ksl == 0) {
        #pragma unroll
        for (int j = 0; j < 6; ++j) Hpart[wv][6 * ng + j] = acc[j];
        if (ng == 0) Hpart[wv][24] = r2;
    }
    __syncthreads();

    // ---- scalar phase: lanes 0..3, one token each (R2-proven) ----
    if (tid < NTOK) {
        const int t = tid;
        float Hp[24];
        #pragma unroll
        for (int q = 0; q < 24; ++q) Hp[q] = Hpart[t][q];
        const float r2v = Hpart[t][24];
        const float r_ = 1.0f / (sqrtf(r2v) * 0.03125f + 1e-6f);

        float Hpre[4], Hpost[4], K[16];
        #pragma unroll
        for (int n = 0; n < 4; ++n)
            Hpre[n] = sigmoid_f(fmaf(r_, Hp[n], beta[n]));
        #pragma unroll
        for (int n = 0; n < 4; ++n)
            Hpost[n] = 2.0f * sigmoid_f(fmaf(r_, Hp[4 + n], beta[4 + n]));
        #pragma unroll
        for (int q = 0; q < 16; ++q)
            K[q] = __expf(fmaf(r_, Hp[8 + q], beta[8 + q]));

        float u0=1.f,u1=1.f,u2=1.f,u3=1.f;
        float v0=1.f,v1=1.f,v2=1.f,v3=1.f;
        for (int itr = 0; itr < 10; ++itr) {
            u0 = 1.0f/(K[0]*v0  + K[1]*v1  + K[2]*v2  + K[3]*v3  + 1e-8f);
            u1 = 1.0f/(K[4]*v0  + K[5]*v1  + K[6]*v2  + K[7]*v3  + 1e-8f);
            u2 = 1.0f/(K[8]*v0  + K[9]*v1  + K[10]*v2 + K[11]*v3 + 1e-8f);
            u3 = 1.0f/(K[12]*v0 + K[13]*v1 + K[14]*v2 + K[15]*v3 + 1e-8f);
            v0 = 1.0f/(K[0]*u0  + K[4]*u1  + K[8]*u2  + K[12]*u3 + 1e-8f);
            v1 = 1.0f/(K[1]*u0  + K[5]*u1  + K[9]*u2  + K[13]*u3 + 1e-8f);
            v2 = 1.0f/(K[2]*u0  + K[6]*u1  + K[10]*u2 + K[14]*u3 + 1e-8f);
            v3 = 1.0f/(K[3]*u0  + K[7]*u1  + K[11]*u2 + K[15]*u3 + 1e-8f);
        }
        smalls[t][0] = Hpre[0];  smalls[t][1] = Hpre[1];
        smalls[t][2] = Hpre[2];  smalls[t][3] = Hpre[3];
        smalls[t][4] = Hpost[0]; smalls[t][5] = Hpost[1];
        smalls[t][6] = Hpost[2]; smalls[t][7] = Hpost[3];
        smalls[t][8]  = u0*K[0]*v0;   smalls[t][9]  = u0*K[1]*v1;
        smalls[t][10] = u0*K[2]*v2;   smalls[t][11] = u0*K[3]*v3;
        smalls[t][12] = u1*K[4]*v0;   smalls[t][13] = u1*K[5]*v1;
        smalls[t][14] = u1*K[6]*v2;   smalls[t][15] = u1*K[7]*v3;
        smalls[t][16] = u2*K[8]*v0;   smalls[t][17] = u2*K[9]*v1;
        smalls[t][18] = u2*K[10]*v2;  smalls[t][19] = u2*K[11]*v3;
        smalls[t][20] = u3*K[12]*v0;  smalls[t][21] = u3*K[13]*v1;
        smalls[t][22] = u3*K[14]*v2;  smalls[t][23] = u3*K[15]*v3;
    }
    __syncthreads();

    // ---- phase C: x from the LDS tile (no global h re-read) ----
    const int gg = wv;   // n = gg, d = 4*lane..+3
    #pragma unroll
    for (int it = 0; it < NTOK; ++it) {
        const float* tl = tile + it * 1024 + 4 * lane;
        const float4 xm0 = *(const float4*)(tl);
        const float4 xm1 = *(const float4*)(tl + 256);
        const float4 xm2 = *(const float4*)(tl + 512);
        const float4 xm3 = *(const float4*)(tl + 768);

        const float hp0 = smalls[it][0], hp1 = smalls[it][1];
        const float hp2 = smalls[it][2], hp3 = smalls[it][3];
        const float hpost = smalls[it][4 + gg];
        const float P0 = smalls[it][8 + 4*gg + 0];
        const float P1 = smalls[it][8 + 4*gg + 1];
        const float P2 = smalls[it][8 + 4*gg + 2];
        const float P3 = smalls[it][8 + 4*gg + 3];

        float4 o;
        {
            const float hpre = hp0*xm0.x + hp1*xm1.x + hp2*xm2.x + hp3*xm3.x;
            o.x = fmaf(hpost, hpre, P0*xm0.x + P1*xm1.x + P2*xm2.x + P3*xm3.x);
        }
        {
            const float hpre = hp0*xm0.y + hp1*xm1.y + hp2*xm2.y + hp3*xm3.y;
            o.y = fmaf(hpost, hpre, P0*xm0.y + P1*xm1.y + P2*xm2.y + P3*xm3.y);
        }
        {
            const float hpre = hp0*xm0.z + hp1*xm1.z + hp2*xm2.z + hp3*xm3.z;
            o.z = fmaf(hpost, hpre, P0*xm0.z + P1*xm1.z + P2*xm2.z + P3*xm3.z);
        }
        {
            const float hpre = hp0*xm0.w + hp1*xm1.w + hp2*xm2.w + hp3*xm3.w;
            o.w = fmaf(hpost, hpre, P0*xm0.w + P1*xm1.w + P2*xm2.w + P3*xm3.w);
        }
        *(float4*)(out + (tok0 + it) * 1024 + gg * 256 + 4 * lane) = o;
    }
}

extern "C" void kernel_launch(void* const* d_in, const int* in_sizes, int n_in,
                              void* d_out, int out_size, void* d_ws, size_t ws_size,
                              hipStream_t stream) {
    const float* h     = (const float*)d_in[0];
    const float* nw    = (const float*)d_in[1];
    const float* w     = (const float*)d_in[2];
    const float* alpha = (const float*)d_in[3];
    const float* beta  = (const float*)d_in[4];
    float* out = (float*)d_out;
    unsigned short* wt = (unsigned short*)d_ws;   // 24*1024*2B = 48KB

    prep_kernel<<<24, 256, 0, stream>>>(nw, w, alpha, wt);
    // 32768 tokens / 4 per block = 8192 blocks
    mhc_kernel<<<8192, 256, 0, stream>>>(h, wt, beta, out);
}

// Round 20
// 76.017 us; speedup vs baseline: 1.5671x; 1.5671x over previous
//
#include <hip/hip_runtime.h>
#include <math.h>

// ManifoldHyperConnectionFuse on MI355X — R19: R18 with the cvt_pkrtz type
// fix (builtin returns __fp16x2, not _Float16x2 -> capture auto + bit_cast).
// Theory unchanged from R18:
//   weight L2 traffic = 48KB x (32768/T): T=4 keeps it at 400MB;
//   f16 weights + f16 x-tile consumed via v_dot2_f32_f16 (fdot2): one inst
//   = 2 MACs, zero unpack VALU (vs 24 unpack ops/iter for bf16);
//   NTOK=16, grid 2048, launch_bounds(256,3) (proven non-throttling),
//   phase C reads the f16 tile (no global h re-read).

#define NTOK 16

typedef __attribute__((ext_vector_type(2))) _Float16 h2v;

__device__ __forceinline__ float fdot2f(unsigned int a, unsigned int b, float c) {
#if __has_builtin(__builtin_amdgcn_fdot2)
    return __builtin_amdgcn_fdot2(__builtin_bit_cast(h2v, a),
                                  __builtin_bit_cast(h2v, b), c, false);
#else
    h2v av = __builtin_bit_cast(h2v, a);
    h2v bv = __builtin_bit_cast(h2v, b);
    return fmaf((float)av[1], (float)bv[1],
           fmaf((float)av[0], (float)bv[0], c));
#endif
}

__device__ __forceinline__ unsigned int pk_f16(float a, float b) {
    const auto p = __builtin_amdgcn_cvt_pkrtz(a, b);   // __fp16x2
    return __builtin_bit_cast(unsigned int, p);
}

__device__ __forceinline__ float sigmoid_f(float z) {
    return 1.0f / (1.0f + __expf(-z));
}

// sum over each aligned 16-lane row via DPP row_ror (VALU-only)
__device__ __forceinline__ float row16_sum(float x) {
    x += __int_as_float(__builtin_amdgcn_update_dpp(
        0, __float_as_int(x), 0x121, 0xf, 0xf, false)); // row_ror:1
    x += __int_as_float(__builtin_amdgcn_update_dpp(
        0, __float_as_int(x), 0x122, 0xf, 0xf, false)); // row_ror:2
    x += __int_as_float(__builtin_amdgcn_update_dpp(
        0, __float_as_int(x), 0x124, 0xf, 0xf, false)); // row_ror:4
    x += __int_as_float(__builtin_amdgcn_update_dpp(
        0, __float_as_int(x), 0x128, 0xf, 0xf, false)); // row_ror:8
    return x;
}

// ---- prep: fold alpha*nw*w -> f16 wt[24][1024] (n-major) in d_ws ----
__global__ __launch_bounds__(256)
void prep_kernel(const float* __restrict__ nw,
                 const float* __restrict__ w,
                 const float* __restrict__ alpha,
                 unsigned short* __restrict__ wt)
{
    const int tid = blockIdx.x * 256 + threadIdx.x;   // 6144 threads
    const int flat = 4 * tid;                          // w is [k][n], flat=k*24+n
    const float4 w4 = *(const float4*)(w + flat);
    const float a0 = alpha[0], a1 = alpha[1], a2 = alpha[2];
    const float vals[4] = {w4.x, w4.y, w4.z, w4.w};
    #pragma unroll
    for (int c = 0; c < 4; ++c) {
        const int f = flat + c;
        const int k = f / 24;
        const int n = f - 24 * k;
        const float as = (n < 4) ? a0 : ((n < 8) ? a1 : a2);
        const unsigned int p = pk_f16(as * nw[k] * vals[c], 0.f);
        wt[n * 1024 + k] = (unsigned short)(p & 0xffffu);
    }
}

__global__ __launch_bounds__(256, 3)
void mhc_kernel(const float* __restrict__ h,
                const unsigned short* __restrict__ wt,
                const float* __restrict__ beta,
                float* __restrict__ out)
{
    const int tid  = threadIdx.x;
    const int lane = tid & 63;
    const int wv   = tid >> 6;     // wave id: owns tokens [4wv, 4wv+4)
    const int ksl  = lane & 15;    // k-slice lane
    const int ng   = lane >> 4;    // n-group (6 n's each)

    __shared__ unsigned int tile[NTOK * 512];  // f16 x-tile, 32KB (uint=2 halfs)
    __shared__ float Hpart[NTOK][28];          // [0:24) H, [24] r2
    __shared__ float smalls[NTOK][26];         // Hpre, Hpost, P

    const long tok0 = (long)blockIdx.x * NTOK;

    // ---- stage: 16 rows, f32 -> f16 pack, 64KB read -> 32KB LDS ----
    {
        const float* src = h + tok0 * 1024 + 4 * tid;
        #pragma unroll
        for (int i = 0; i < NTOK; ++i) {
            const float4 v = *(const float4*)(src + 1024 * i);
            uint2 u;
            u.x = pk_f16(v.x, v.y);
            u.y = pk_f16(v.z, v.w);
            *(uint2*)(tile + i * 512 + 2 * tid) = u;
        }
    }
    __syncthreads();

    // ---- phase A: 4 tokens/wave, fdot2 MACs, w from d_ws (L2-hot) ----
    const int t0 = 4 * wv;
    // uint2 index: x at (t*1024 + 4*ksl)/4 ; w at ((6ng+j)*1024 + 4*ksl)/4
    const uint2* txp = (const uint2*)tile + t0 * 256 + ksl;
    const uint2* twp = (const uint2*)wt + (6 * ng) * 256 + ksl;

    float acc[4][6], r2[4];
    #pragma unroll
    for (int t = 0; t < 4; ++t) {
        r2[t] = 0.f;
        #pragma unroll
        for (int j = 0; j < 6; ++j) acc[t][j] = 0.f;
    }

    #pragma unroll 1
    for (int e = 0; e < 16; ++e) {
        uint2 xw[4];
        #pragma unroll
        for (int t = 0; t < 4; ++t) xw[t] = txp[t * 256 + e * 16];   // LDS b64
        uint2 wr[6];
        #pragma unroll
        for (int j = 0; j < 6; ++j) wr[j] = twp[j * 256 + e * 16];   // L2

        #pragma unroll
        for (int j = 0; j < 6; ++j) {
            #pragma unroll
            for (int t = 0; t < 4; ++t) {
                acc[t][j] = fdot2f(xw[t].y, wr[j].y,
                            fdot2f(xw[t].x, wr[j].x, acc[t][j]));
            }
        }
        #pragma unroll
        for (int t = 0; t < 4; ++t) {
            r2[t] = fdot2f(xw[t].y, xw[t].y,
                    fdot2f(xw[t].x, xw[t].x, r2[t]));
        }
    }

    // ---- DPP reduce over ksl -> FINAL H for this wave's 4 tokens ----
    #pragma unroll
    for (int t = 0; t < 4; ++t) {
        #pragma unroll
        for (int j = 0; j < 6; ++j) acc[t][j] = row16_sum(acc[t][j]);
        r2[t] = row16_sum(r2[t]);
    }
    if (ksl == 0) {
        #pragma unroll
        for (int t = 0; t < 4; ++t) {
            #pragma unroll
            for (int j = 0; j < 6; ++j)
                Hpart[t0 + t][6 * ng + j] = acc[t][j];
            if (ng == 0) Hpart[t0 + t][24] = r2[t];
        }
    }
    __syncthreads();

    // ---- scalar phase: lanes 0..15, one token each (R2-proven) ----
    if (tid < NTOK) {
        const int t = tid;
        float Hp[24];
        #pragma unroll
        for (int q = 0; q < 24; ++q) Hp[q] = Hpart[t][q];
        const float r2v = Hpart[t][24];
        const float r_ = 1.0f / (sqrtf(r2v) * 0.03125f + 1e-6f);

        float Hpre[4], Hpost[4], K[16];
        #pragma unroll
        for (int n = 0; n < 4; ++n)
            Hpre[n] = sigmoid_f(fmaf(r_, Hp[n], beta[n]));
        #pragma unroll
        for (int n = 0; n < 4; ++n)
            Hpost[n] = 2.0f * sigmoid_f(fmaf(r_, Hp[4 + n], beta[4 + n]));
        #pragma unroll
        for (int q = 0; q < 16; ++q)
            K[q] = __expf(fmaf(r_, Hp[8 + q], beta[8 + q]));

        float u0=1.f,u1=1.f,u2=1.f,u3=1.f;
        float v0=1.f,v1=1.f,v2=1.f,v3=1.f;
        for (int itr = 0; itr < 10; ++itr) {
            u0 = 1.0f/(K[0]*v0  + K[1]*v1  + K[2]*v2  + K[3]*v3  + 1e-8f);
            u1 = 1.0f/(K[4]*v0  + K[5]*v1  + K[6]*v2  + K[7]*v3  + 1e-8f);
            u2 = 1.0f/(K[8]*v0  + K[9]*v1  + K[10]*v2 + K[11]*v3 + 1e-8f);
            u3 = 1.0f/(K[12]*v0 + K[13]*v1 + K[14]*v2 + K[15]*v3 + 1e-8f);
            v0 = 1.0f/(K[0]*u0  + K[4]*u1  + K[8]*u2  + K[12]*u3 + 1e-8f);
            v1 = 1.0f/(K[1]*u0  + K[5]*u1  + K[9]*u2  + K[13]*u3 + 1e-8f);
            v2 = 1.0f/(K[2]*u0  + K[6]*u1  + K[10]*u2 + K[14]*u3 + 1e-8f);
            v3 = 1.0f/(K[3]*u0  + K[7]*u1  + K[11]*u2 + K[15]*u3 + 1e-8f);
        }
        smalls[t][0] = Hpre[0];  smalls[t][1] = Hpre[1];
        smalls[t][2] = Hpre[2];  smalls[t][3] = Hpre[3];
        smalls[t][4] = Hpost[0]; smalls[t][5] = Hpost[1];
        smalls[t][6] = Hpost[2]; smalls[t][7] = Hpost[3];
        smalls[t][8]  = u0*K[0]*v0;   smalls[t][9]  = u0*K[1]*v1;
        smalls[t][10] = u0*K[2]*v2;   smalls[t][11] = u0*K[3]*v3;
        smalls[t][12] = u1*K[4]*v0;   smalls[t][13] = u1*K[5]*v1;
        smalls[t][14] = u1*K[6]*v2;   smalls[t][15] = u1*K[7]*v3;
        smalls[t][16] = u2*K[8]*v0;   smalls[t][17] = u2*K[9]*v1;
        smalls[t][18] = u2*K[10]*v2;  smalls[t][19] = u2*K[11]*v3;
        smalls[t][20] = u3*K[12]*v0;  smalls[t][21] = u3*K[13]*v1;
        smalls[t][22] = u3*K[14]*v2;  smalls[t][23] = u3*K[15]*v3;
    }
    __syncthreads();

    // ---- phase C: x from f16 tile (no global h re-read) ----
    const int gg = wv;   // n = gg, d = 4*lane..+3
    for (int it = 0; it < NTOK; ++it) {
        // lane reads 4 halfs at d=4*lane for each m: uint2 idx it*256+m*64+lane
        const uint2* tl = (const uint2*)tile + it * 256 + lane;
        float xm[4][4];
        #pragma unroll
        for (int m = 0; m < 4; ++m) {
            const uint2 u = tl[m * 64];
            const h2v p0 = __builtin_bit_cast(h2v, u.x);
            const h2v p1 = __builtin_bit_cast(h2v, u.y);
            xm[m][0] = (float)p0[0]; xm[m][1] = (float)p0[1];
            xm[m][2] = (float)p1[0]; xm[m][3] = (float)p1[1];
        }

        const float hp0 = smalls[it][0], hp1 = smalls[it][1];
        const float hp2 = smalls[it][2], hp3 = smalls[it][3];
        const float hpost = smalls[it][4 + gg];
        const float P0 = smalls[it][8 + 4*gg + 0];
        const float P1 = smalls[it][8 + 4*gg + 1];
        const float P2 = smalls[it][8 + 4*gg + 2];
        const float P3 = smalls[it][8 + 4*gg + 3];

        float4 o;
        #pragma unroll
        for (int c = 0; c < 4; ++c) {
            const float hpre = hp0*xm[0][c] + hp1*xm[1][c]
                             + hp2*xm[2][c] + hp3*xm[3][c];
            const float res  = P0*xm[0][c] + P1*xm[1][c]
                             + P2*xm[2][c] + P3*xm[3][c];
            ((float*)&o)[c] = fmaf(hpost, hpre, res);
        }
        *(float4*)(out + (tok0 + it) * 1024 + gg * 256 + 4 * lane) = o;
    }
}

extern "C" void kernel_launch(void* const* d_in, const int* in_sizes, int n_in,
                              void* d_out, int out_size, void* d_ws, size_t ws_size,
                              hipStream_t stream) {
    const float* h     = (const float*)d_in[0];
    const float* nw    = (const float*)d_in[1];
    const float* w     = (const float*)d_in[2];
    const float* alpha = (const float*)d_in[3];
    const float* beta  = (const float*)d_in[4];
    float* out = (float*)d_out;
    unsigned short* wt = (unsigned short*)d_ws;   // 24*1024*2B = 48KB

    prep_kernel<<<24, 256, 0, stream>>>(nw, w, alpha, wt);
    // 32768 tokens / 16 per block = 2048 blocks
    mhc_kernel<<<2048, 256, 0, stream>>>(h, wt, beta, out);
}